// Round 12
// baseline (580.014 us; speedup 1.0000x reference)
//
#include <hip/hip_runtime.h>
#include <hip/hip_fp16.h>

#define NN 100000
#define NE 1600000
#define KD 128
#define EPSF 1e-5f
#define RNG2 200                    // fine dst-ranges (1 sort block each)
#define RSZ2 500                    // nodes per range (200*500 = NN exactly)
#define BE 4096                     // edges per bucket block
#define BG ((NE + BE - 1) / BE)     // 391 bucket blocks
#define BCAP2 10000                 // per-range capacity (mean 8000, +22 sigma)
#define WPLANE 16384                // 128*128 weight plane (ushort elems)
#define LDK 136                     // LDS K-stride (128 + 8 pad)
#define WCB 168                     // wconv blocks (43008/256)

typedef __attribute__((ext_vector_type(8))) _Float16 f16x8;
typedef __attribute__((ext_vector_type(8))) unsigned short ushort8;
typedef __attribute__((ext_vector_type(4))) unsigned short ushort4v;
typedef __attribute__((ext_vector_type(4))) float f32x4;

// ---- fp16 helpers ----
__device__ __forceinline__ unsigned short f2h(float f) {
    __half h = __float2half_rn(f);
    return *reinterpret_cast<unsigned short*>(&h);
}
__device__ __forceinline__ float h2f(unsigned short u) {
    __half h;
    *reinterpret_cast<unsigned short*>(&h) = u;
    return __half2float(h);
}
__device__ __forceinline__ float2 h2f2(unsigned u) {
    __half2 h = *reinterpret_cast<const __half2*>(&u);
    return __half22float2(h);
}

// ---------------------------------------------------------------- init ----
__global__ void zero_init_kernel(float* __restrict__ bnacc, int* __restrict__ gcur) {
    int i = threadIdx.x;
    if (i < 512) bnacc[i] = 0.0f;
    if (i < RNG2) gcur[i] = 0;
}

// ---------------------------------------------------------- bucketing ----
__global__ __launch_bounds__(256) void bucket_kernel(
    const int* __restrict__ src, const int* __restrict__ dst,
    int* __restrict__ gcur, unsigned* __restrict__ bP) {
    __shared__ int lhist[RNG2];
    __shared__ int lbase[RNG2];
    __shared__ int lcur[RNG2];
    const int t = threadIdx.x;
    const int e0 = blockIdx.x * BE;
    const int e1 = min(e0 + BE, NE);
    if (t < RNG2) { lhist[t] = 0; lcur[t] = 0; }
    __syncthreads();
    int dv[16], sv[16], rr[16];
    int nv = 0;
#pragma unroll
    for (int i = 0; i < 16; i++) {
        int e = e0 + i * 256 + t;
        if (e < e1) {
            int d = __builtin_nontemporal_load(&dst[e]);
            int s = __builtin_nontemporal_load(&src[e]);
            dv[i] = d; sv[i] = s;
            rr[i] = (int)((unsigned)d / RSZ2);
            nv = i + 1;              // validity is an i-prefix for fixed t
            atomicAdd(&lhist[rr[i]], 1);
        }
    }
    __syncthreads();
    if (t < RNG2) lbase[t] = lhist[t] ? atomicAdd(&gcur[t], lhist[t]) : 0;
    __syncthreads();
#pragma unroll
    for (int i = 0; i < 16; i++) {
        if (i < nv) {
            int r = rr[i];
            int p = lbase[r] + atomicAdd(&lcur[r], 1);
            if (p < BCAP2)
                bP[(size_t)r * BCAP2 + p] =
                    ((unsigned)sv[i] << 9) | (unsigned)(dv[i] - r * RSZ2);
        }
    }
}

// ------------------------------------------------- per-range LDS sort ----
__global__ __launch_bounds__(512) void sort_range_kernel(
    const unsigned* __restrict__ bP, const int* __restrict__ gcur,
    int* __restrict__ row_start, float* __restrict__ deg_inv,
    int* __restrict__ sorted_src) {
    __shared__ int s[512];
    __shared__ int cnt[RSZ2];
    __shared__ int cur[RSZ2];
    __shared__ int sbase;
    const int r = blockIdx.x;
    const int t = threadIdx.x;

    // global base = prefix over the 200 range totals
    int v = (t < RNG2) ? gcur[t] : 0;
    s[t] = v;
    __syncthreads();
    for (int off = 1; off < 512; off <<= 1) {
        int u = (t >= off) ? s[t - off] : 0;
        __syncthreads();
        s[t] += u;
        __syncthreads();
    }
    if (t == 0) sbase = (r == 0) ? 0 : s[r - 1];
    if (t < RSZ2) cnt[t] = 0;
    __syncthreads();

    const int n = gcur[r];
    const unsigned* b = &bP[(size_t)r * BCAP2];
    for (int i = t; i < n; i += 512) {
        unsigned u = __builtin_nontemporal_load(&b[i]);
        atomicAdd(&cnt[u & 511u], 1);
    }
    __syncthreads();

    // exclusive scan of cnt[0..RSZ2)
    int c = (t < RSZ2) ? cnt[t] : 0;
    s[t] = c;
    __syncthreads();
    for (int off = 1; off < 512; off <<= 1) {
        int u = (t >= off) ? s[t - off] : 0;
        __syncthreads();
        s[t] += u;
        __syncthreads();
    }
    const int base = sbase;
    if (t < RSZ2) {
        int excl = s[t] - c;
        cur[t] = excl;
        int g = r * RSZ2 + t;
        row_start[g] = base + excl;
        deg_inv[g] = 1.0f / (float)(c > 1 ? c : 1);
    }
    if (r == RNG2 - 1 && t == 0) row_start[NN] = NE;
    __syncthreads();

    for (int i = t; i < n; i += 512) {
        unsigned u = __builtin_nontemporal_load(&b[i]);
        int d = (int)(u & 511u);
        int p = atomicAdd(&cur[d], 1);
        sorted_src[base + p] = (int)(u >> 9);
    }
}

// ---------------------------------------------------------- converters ----
__global__ void wx_kernel(const float* w0, const float* w1, const float* w2,
                          const float* w3, const float* w4, const float* w5,
                          const float* w6, const float* w7, const float* w8,
                          const float* w9, const float* w10,
                          unsigned short* __restrict__ P,
                          const float* __restrict__ X, unsigned short* __restrict__ Xh) {
    if (blockIdx.x < WCB) {
        int i = blockIdx.x * 256 + threadIdx.x;  // float4 index
        if (i >= 43008) return;                  // 10*4096 + 2048
        int seg = i >> 12;
        const float* srcs[11] = {w0, w1, w2, w3, w4, w5, w6, w7, w8, w9, w10};
        const float* s = srcs[seg];
        int off = i - (seg << 12);
        float4 v = ((const float4*)s)[off];
        ushort4v h, l;
        h.x = f2h(v.x); l.x = f2h(v.x - h2f(h.x));
        h.y = f2h(v.y); l.y = f2h(v.y - h2f(h.y));
        h.z = f2h(v.z); l.z = f2h(v.z - h2f(h.z));
        h.w = f2h(v.w); l.w = f2h(v.w - h2f(h.w));
        // fragment-order output index
        int col = off >> 5;          // 0..127 (0..63 for clf)
        int k4  = off & 31;          // float4 along k
        int cg = col >> 4, mm = col & 15;
        int k = k4 * 4;
        int ks = k >> 5, q = (k >> 3) & 3, ii = k & 7;   // ii in {0,4}
        int po = ((cg * 4 + ks) * 64 + q * 16 + mm) * 8 + ii;
        *(ushort4v*)&P[(size_t)seg * WPLANE + po] = h;
        *(ushort4v*)&P[(size_t)(11 + seg) * WPLANE + po] = l;
    } else {
        int idx = (blockIdx.x - WCB) * 256 + threadIdx.x;
        if (idx >= NN * KD / 4) return;
        float4 v = ((const float4*)X)[idx];
        ushort4v h;
        h.x = f2h(v.x); h.y = f2h(v.y); h.z = f2h(v.z); h.w = f2h(v.w);
        *(ushort4v*)&Xh[(size_t)idx * 4] = h;
    }
}

// ------------------------------------------------------------ aggregate ----
__global__ void aggregate_kernel(const unsigned short* __restrict__ Xh,
                                 const int* __restrict__ row_start,
                                 const int* __restrict__ sorted_src,
                                 const float* __restrict__ deg_inv,
                                 unsigned short* __restrict__ Mh) {
    int node = blockIdx.x * 16 + (threadIdx.x >> 4);
    int lane = threadIdx.x & 15;
    if (node >= NN) return;
    int e0 = row_start[node];
    int e1 = row_start[node + 1];
    float4 a0 = {0, 0, 0, 0}, a1 = {0, 0, 0, 0};
    float4 b0 = {0, 0, 0, 0}, b1 = {0, 0, 0, 0};

    auto ld = [&](int e) -> uint4 {
        int s = sorted_src[e];
        return *(const uint4*)&Xh[(size_t)s * KD + lane * 8];
    };
    auto addq = [](float4& x, float4& y, uint4 u) {
        float2 p0 = h2f2(u.x), p1 = h2f2(u.y), p2 = h2f2(u.z), p3 = h2f2(u.w);
        x.x += p0.x; x.y += p0.y; x.z += p1.x; x.w += p1.y;
        y.x += p2.x; y.y += p2.y; y.z += p3.x; y.w += p3.y;
    };

    int e = e0;
    for (; e + 8 <= e1; e += 8) {
        uint4 u0 = ld(e + 0), u1 = ld(e + 1), u2 = ld(e + 2), u3 = ld(e + 3);
        uint4 u4 = ld(e + 4), u5 = ld(e + 5), u6 = ld(e + 6), u7 = ld(e + 7);
        addq(a0, a1, u0); addq(b0, b1, u1); addq(a0, a1, u2); addq(b0, b1, u3);
        addq(a0, a1, u4); addq(b0, b1, u5); addq(a0, a1, u6); addq(b0, b1, u7);
    }
    for (; e + 2 <= e1; e += 2) {
        uint4 u0 = ld(e + 0), u1 = ld(e + 1);
        addq(a0, a1, u0); addq(b0, b1, u1);
    }
    if (e < e1) { uint4 u = ld(e); addq(a0, a1, u); }

    float di = deg_inv[node];
    ushort8 o;
    o[0] = f2h((a0.x + b0.x) * di);
    o[1] = f2h((a0.y + b0.y) * di);
    o[2] = f2h((a0.z + b0.z) * di);
    o[3] = f2h((a0.w + b0.w) * di);
    o[4] = f2h((a1.x + b1.x) * di);
    o[5] = f2h((a1.y + b1.y) * di);
    o[6] = f2h((a1.z + b1.z) * di);
    o[7] = f2h((a1.w + b1.w) * di);
    *(ushort8*)&Mh[(size_t)node * KD + lane * 8] = o;
}

// ---------------------------------------------------- fused GEMM helpers ----
// Fragment layout (verified R4-R8): A[m=lane&15][k=quad*8+j]; C/D col=lane&15,
// row=quad*4+reg. Weights pre-permuted: load = base(cg,ks) + lane*16B.
// A loads DIRECT FROM GLOBAL (R12): lane reads A[(i0+mt*16+mm)*KD+ks*32+quad*8]
// -- 16x64B segments/instruction (same line count as coalesced), 4 waves of a
// block share the tile via L1. Removes LDS staging and ALL pre-epilogue
// barriers (the R11 barrier convoy was the sage bottleneck).

template <int NT>
__device__ __forceinline__ void productG_A16(
    const unsigned short* __restrict__ A, int i0,
    const unsigned short* __restrict__ Wh, const unsigned short* __restrict__ Wl,
    int colb, int quad, int mm, f32x4 (&acc)[4][NT]) {
    const int l8 = (quad * 16 + mm) * 8;
    const int cg0 = colb >> 4;
#pragma unroll
    for (int ks = 0; ks < 4; ks++) {
        f16x8 a[4];
#pragma unroll
        for (int mt = 0; mt < 4; mt++) {
            int gi = min(i0 + mt * 16 + mm, NN - 1);
            a[mt] = *(const f16x8*)&A[(size_t)gi * KD + ks * 32 + quad * 8];
        }
#pragma unroll
        for (int nt = 0; nt < NT; nt++) {
            size_t wo = (size_t)(((cg0 + nt) * 4 + ks) << 9) + l8;
            f16x8 wh = *(const f16x8*)&Wh[wo];
            f16x8 wl = *(const f16x8*)&Wl[wo];
#pragma unroll
            for (int mt = 0; mt < 4; mt++) {
                acc[mt][nt] = __builtin_amdgcn_mfma_f32_16x16x32_f16(a[mt], wh, acc[mt][nt], 0, 0, 0);
                acc[mt][nt] = __builtin_amdgcn_mfma_f32_16x16x32_f16(a[mt], wl, acc[mt][nt], 0, 0, 0);
            }
        }
    }
}

// dual product from global A: two weight matrices share the A loads
template <int NT>
__device__ __forceinline__ void product2G_A16(
    const unsigned short* __restrict__ A, int i0,
    const unsigned short* __restrict__ W1h, const unsigned short* __restrict__ W1l,
    const unsigned short* __restrict__ W2h, const unsigned short* __restrict__ W2l,
    int colb, int quad, int mm, f32x4 (&acc1)[4][NT], f32x4 (&acc2)[4][NT]) {
    const int l8 = (quad * 16 + mm) * 8;
    const int cg0 = colb >> 4;
#pragma unroll
    for (int ks = 0; ks < 4; ks++) {
        f16x8 a[4];
#pragma unroll
        for (int mt = 0; mt < 4; mt++) {
            int gi = min(i0 + mt * 16 + mm, NN - 1);
            a[mt] = *(const f16x8*)&A[(size_t)gi * KD + ks * 32 + quad * 8];
        }
#pragma unroll
        for (int nt = 0; nt < NT; nt++) {
            size_t wo = (size_t)(((cg0 + nt) * 4 + ks) << 9) + l8;
            f16x8 w1h = *(const f16x8*)&W1h[wo];
            f16x8 w1l = *(const f16x8*)&W1l[wo];
            f16x8 w2h = *(const f16x8*)&W2h[wo];
            f16x8 w2l = *(const f16x8*)&W2l[wo];
#pragma unroll
            for (int mt = 0; mt < 4; mt++) {
                acc1[mt][nt] = __builtin_amdgcn_mfma_f32_16x16x32_f16(a[mt], w1h, acc1[mt][nt], 0, 0, 0);
                acc1[mt][nt] = __builtin_amdgcn_mfma_f32_16x16x32_f16(a[mt], w1l, acc1[mt][nt], 0, 0, 0);
                acc2[mt][nt] = __builtin_amdgcn_mfma_f32_16x16x32_f16(a[mt], w2h, acc2[mt][nt], 0, 0, 0);
                acc2[mt][nt] = __builtin_amdgcn_mfma_f32_16x16x32_f16(a[mt], w2l, acc2[mt][nt], 0, 0, 0);
            }
        }
    }
}

// split-A product (A = Ah + Al fp16 LDS planes, exact intermediates): 3 MFMA
template <int NT>
__device__ __forceinline__ void productS_A16(
    const unsigned short* Ph, const unsigned short* Pl,
    const unsigned short* __restrict__ Wh, const unsigned short* __restrict__ Wl,
    int colb, int quad, int mm, f32x4 (&acc)[4][NT]) {
    const int l8 = (quad * 16 + mm) * 8;
    const int cg0 = colb >> 4;
#pragma unroll
    for (int ks = 0; ks < 4; ks++) {
        f16x8 ah[4], al[4];
#pragma unroll
        for (int mt = 0; mt < 4; mt++) {
            int off = (mt * 16 + mm) * LDK + ks * 32 + quad * 8;
            ah[mt] = *(const f16x8*)&Ph[off];
            al[mt] = *(const f16x8*)&Pl[off];
        }
#pragma unroll
        for (int nt = 0; nt < NT; nt++) {
            size_t wo = (size_t)(((cg0 + nt) * 4 + ks) << 9) + l8;
            f16x8 wh = *(const f16x8*)&Wh[wo];
            f16x8 wl = *(const f16x8*)&Wl[wo];
#pragma unroll
            for (int mt = 0; mt < 4; mt++) {
                acc[mt][nt] = __builtin_amdgcn_mfma_f32_16x16x32_f16(ah[mt], wh, acc[mt][nt], 0, 0, 0);
                acc[mt][nt] = __builtin_amdgcn_mfma_f32_16x16x32_f16(ah[mt], wl, acc[mt][nt], 0, 0, 0);
                acc[mt][nt] = __builtin_amdgcn_mfma_f32_16x16x32_f16(al[mt], wh, acc[mt][nt], 0, 0, 0);
            }
        }
    }
}

// ------------------------------------------------- fused sage+res+stats ----
// Direct-global A products -> ONE barrier total (epilogue LDS transpose).
__global__ __launch_bounds__(256, 4) void fused_sage_kernel(
    const unsigned short* __restrict__ A1h, const unsigned short* __restrict__ A2h,
    const unsigned short* __restrict__ Wlh, const unsigned short* __restrict__ Wll,
    const unsigned short* __restrict__ Wrh, const unsigned short* __restrict__ Wrl,
    const unsigned short* __restrict__ Weh, const unsigned short* __restrict__ Wel,
    const float* __restrict__ bs, const float* __restrict__ br,
    unsigned short* __restrict__ B0h, unsigned short* __restrict__ B1h,
    float* __restrict__ bnacc) {
    __shared__ __align__(16) unsigned short P1[64 * LDK];
    __shared__ __align__(16) unsigned short P2[64 * LDK];
    const int t = threadIdx.x;
    const int i0 = blockIdx.x * 64;
    const int w = t >> 6, lane = t & 63, quad = lane >> 4, mm = lane & 15;
    const int colb = w * 32;

    f32x4 accs[4][2] = {};
    productG_A16<2>(A1h, i0, Wlh, Wll, colb, quad, mm, accs);
    f32x4 accr[4][2] = {};
    product2G_A16<2>(A2h, i0, Wrh, Wrl, Weh, Wel, colb, quad, mm, accs, accr);

    // BN stats from fp32 accs (+bias); full-tile fast path (only last block partial)
    float s[2] = {0, 0}, q[2] = {0, 0};
    if (i0 + 64 <= NN) {
#pragma unroll
        for (int nt = 0; nt < 2; nt++) {
            float bvs = bs[colb + nt * 16 + mm];
#pragma unroll
            for (int mt = 0; mt < 4; mt++)
#pragma unroll
                for (int r = 0; r < 4; r++) {
                    float vs = accs[mt][nt][r] + bvs;
                    s[nt] += vs;
                    q[nt] += vs * vs;
                }
        }
    } else {
#pragma unroll
        for (int nt = 0; nt < 2; nt++) {
            float bvs = bs[colb + nt * 16 + mm];
#pragma unroll
            for (int mt = 0; mt < 4; mt++)
#pragma unroll
                for (int r = 0; r < 4; r++) {
                    if (i0 + mt * 16 + quad * 4 + r < NN) {
                        float vs = accs[mt][nt][r] + bvs;
                        s[nt] += vs;
                        q[nt] += vs * vs;
                    }
                }
        }
    }

    // epilogue: both results to LDS (first LDS touch -> no barrier before),
    // one sync, dual row-stores
#pragma unroll
    for (int nt = 0; nt < 2; nt++) {
        int col = colb + nt * 16 + mm;
        float bvs = bs[col], bvr = br[col];
#pragma unroll
        for (int mt = 0; mt < 4; mt++)
#pragma unroll
            for (int r = 0; r < 4; r++) {
                int row = mt * 16 + quad * 4 + r;
                P1[row * LDK + col] = f2h(accs[mt][nt][r] + bvs);
                P2[row * LDK + col] = f2h(accr[mt][nt][r] + bvr);
            }
    }
    __syncthreads();
    {
        const int orow = t >> 2, ocs = (t & 3) * 32;
        const int go = i0 + orow;
        if (go < NN) {
#pragma unroll
            for (int j = 0; j < 4; j++) {
                *(ushort8*)&B0h[(size_t)go * KD + ocs + j * 8] =
                    *(const ushort8*)&P1[orow * LDK + ocs + j * 8];
                *(ushort8*)&B1h[(size_t)go * KD + ocs + j * 8] =
                    *(const ushort8*)&P2[orow * LDK + ocs + j * 8];
            }
        }
    }

#pragma unroll
    for (int nt = 0; nt < 2; nt++) {
        float ss = s[nt], qq = q[nt];
        ss += __shfl_xor(ss, 16); ss += __shfl_xor(ss, 32);
        qq += __shfl_xor(qq, 16); qq += __shfl_xor(qq, 32);
        if (quad == 0) {
            int col = colb + nt * 16 + mm;
            atomicAdd(&bnacc[col], ss);
            atomicAdd(&bnacc[128 + col], qq);
        }
    }
}

// ----------------------------------------- fused block3: sage3+ff1+ff2+clf ----
__global__ __launch_bounds__(256, 4) void fused_block3_kernel(
    const unsigned short* __restrict__ Mh, const unsigned short* __restrict__ Hw,
    const unsigned short* __restrict__ Wlh, const unsigned short* __restrict__ Wll,
    const unsigned short* __restrict__ Wrh, const unsigned short* __restrict__ Wrl,
    const unsigned short* __restrict__ F1h, const unsigned short* __restrict__ F1l,
    const unsigned short* __restrict__ F2h, const unsigned short* __restrict__ F2l,
    const unsigned short* __restrict__ Ch,  const unsigned short* __restrict__ Cl,
    const float* __restrict__ s3_b, const float* __restrict__ ff1_b,
    const float* __restrict__ ff2_b, const float* __restrict__ clf_b,
    float* __restrict__ out) {
    __shared__ __align__(16) unsigned short Ph[64 * LDK];
    __shared__ __align__(16) unsigned short Pl[64 * LDK];
    const int t = threadIdx.x;
    const int i0 = blockIdx.x * 64;
    const int w = t >> 6, lane = t & 63, quad = lane >> 4, mm = lane & 15;
    const int colb = w * 32;

    // write acc (+bias, opt relu) as exact fp16 hi/lo planes back into LDS
    auto write_lds = [&](f32x4 (&acc)[4][2], const float* bias, bool relu) {
#pragma unroll
        for (int nt = 0; nt < 2; nt++) {
            int col = colb + nt * 16 + mm;
            float bv = bias[col];
#pragma unroll
            for (int mt = 0; mt < 4; mt++)
#pragma unroll
                for (int r = 0; r < 4; r++) {
                    int row = mt * 16 + quad * 4 + r;
                    float v = acc[mt][nt][r] + bv;
                    if (relu) v = fmaxf(v, 0.0f);
                    unsigned short h = f2h(v);
                    Ph[row * LDK + col] = h;
                    Pl[row * LDK + col] = f2h(v - h2f(h));
                }
        }
    };

    // ---- sage3: mean @ Wl + h @ Wr + b (direct-global A, no staging) ----
    f32x4 acc[4][2] = {};
    productG_A16<2>(Mh, i0, Wlh, Wll, colb, quad, mm, acc);
    productG_A16<2>(Hw, i0, Wrh, Wrl, colb, quad, mm, acc);
    write_lds(acc, s3_b, false);          // first LDS touch -> no barrier before
    __syncthreads();

    // ---- ff1 (+relu) ----
    f32x4 acc2[4][2] = {};
    productS_A16<2>(Ph, Pl, F1h, F1l, colb, quad, mm, acc2);
    __syncthreads();
    write_lds(acc2, ff1_b, true);
    __syncthreads();

    // ---- ff2 ----
    f32x4 acc3[4][2] = {};
    productS_A16<2>(Ph, Pl, F2h, F2l, colb, quad, mm, acc3);
    __syncthreads();
    write_lds(acc3, ff2_b, false);
    __syncthreads();

    // ---- clf (NOUT=64): waves cover cols w*16..w*16+15 ----
    f32x4 acc4[4][1] = {};
    productS_A16<1>(Ph, Pl, Ch, Cl, w * 16, quad, mm, acc4);
    __syncthreads();                       // LDS reads done; reuse Ph as f32 region
    {
        float* Pf = (float*)Ph;            // [64][68] f32 (68-stride kills bank clash)
        int col = w * 16 + mm;
        float bv = clf_b[col];
#pragma unroll
        for (int mt = 0; mt < 4; mt++)
#pragma unroll
            for (int r = 0; r < 4; r++)
                Pf[(mt * 16 + quad * 4 + r) * 68 + col] = acc4[mt][0][r] + bv;
        __syncthreads();
        int orow = t >> 2, of4 = (t & 3) * 4;
        if (i0 + orow < NN) {
#pragma unroll
            for (int j = 0; j < 4; j++)
                *(float4*)&out[(size_t)(i0 + orow) * 64 + (of4 + j) * 4] =
                    *(const float4*)&Pf[orow * 68 + (of4 + j) * 4];
        }
    }
}

// ------------------------------------------------------------------ BN ----
// h = relu(Y*scale+shift)+R -> fp16, 8 elems/thread; BN finalize inline.
__global__ void bnrelures_kernel(const unsigned short* __restrict__ Y,
                                 const unsigned short* __restrict__ R,
                                 const float* __restrict__ acc,
                                 const float* __restrict__ g,
                                 const float* __restrict__ b,
                                 unsigned short* __restrict__ Hw) {
    int idx = blockIdx.x * blockDim.x + threadIdx.x;
    const int total = NN * KD / 8;
    if (idx >= total) return;
    int cg = idx & 15;                       // 16 col-groups of 8
    float sc[8], sh[8];
#pragma unroll
    for (int j = 0; j < 8; j++) {
        int col = cg * 8 + j;
        float mean = acc[col] * (1.0f / NN);
        float var = acc[128 + col] * (1.0f / NN) - mean * mean;
        float s = g[col] * rsqrtf(var + EPSF);
        sc[j] = s;
        sh[j] = b[col] - mean * s;
    }
    ushort8 y = *(const ushort8*)&Y[(size_t)idx * 8];
    ushort8 r = *(const ushort8*)&R[(size_t)idx * 8];
    ushort8 hh;
#pragma unroll
    for (int j = 0; j < 8; j++) {
        float f = fmaxf(h2f(y[j]) * sc[j] + sh[j], 0.0f) + h2f(r[j]);
        hh[j] = f2h(f);
    }
    *(ushort8*)&Hw[(size_t)idx * 8] = hh;
}

// --------------------------------------------------------------- launch ----
extern "C" void kernel_launch(void* const* d_in, const int* in_sizes, int n_in,
                              void* d_out, int out_size, void* d_ws, size_t ws_size,
                              hipStream_t stream) {
    const float* x      = (const float*)d_in[0];
    const int*   ei     = (const int*)d_in[1];
    const int*   e_src  = ei;
    const int*   e_dst  = ei + NE;
    const float* s1_b   = (const float*)d_in[4];
    const float* s2_b   = (const float*)d_in[7];
    const float* s3_b   = (const float*)d_in[10];
    const float* bn1_g  = (const float*)d_in[11];
    const float* bn1_b  = (const float*)d_in[12];
    const float* bn2_g  = (const float*)d_in[13];
    const float* bn2_b  = (const float*)d_in[14];
    const float* res1_b = (const float*)d_in[16];
    const float* res2_b = (const float*)d_in[18];
    const float* ff1_b  = (const float*)d_in[20];
    const float* ff2_b  = (const float*)d_in[22];
    const float* clf_b  = (const float*)d_in[24];
    float* out = (float*)d_out;

    // workspace carve-up (256B aligned)
    char* w = (char*)d_ws;
    auto alloc = [&](size_t bytes) { char* p = w; w += (bytes + 255) & ~(size_t)255; return p; };
    unsigned short* B0h = (unsigned short*)alloc((size_t)NN * KD * 2);  // sage out fp16
    unsigned short* B1h = (unsigned short*)alloc((size_t)NN * KD * 2);  // res out fp16
    unsigned short* Mh  = (unsigned short*)alloc((size_t)NN * KD * 2);  // mean fp16
    unsigned short* Hw  = (unsigned short*)alloc((size_t)NN * KD * 2);  // x/h fp16
    int*   row_start = (int*)alloc((NN + 1) * 4);
    int*   sorted    = (int*)alloc((size_t)NE * 4);
    unsigned* bP     = (unsigned*)alloc((size_t)RNG2 * BCAP2 * 4);  // edge buckets (8 MB)
    int*   gcur      = (int*)alloc(RNG2 * 4);
    float* deg_inv   = (float*)alloc(NN * 4);
    float* bnacc     = (float*)alloc(512 * 4);
    unsigned short* Wpl = (unsigned short*)alloc((size_t)22 * WPLANE * 2);

    auto WH = [&](int j) { return Wpl + (size_t)j * WPLANE; };
    auto WL = [&](int j) { return Wpl + (size_t)(11 + j) * WPLANE; };

    const int GG = (NN + 63) / 64;                 // 1563 fused-GEMM blocks
    const int GA = (NN + 15) / 16;                 // 6250 aggregate blocks
    const int GV = (NN * KD / 4 + 255) / 256;      // 12500 xhalf blocks
    const int GV8 = (NN * KD / 8 + 255) / 256;

    // ---- CSR build: bucket -> per-range LDS counting sort (2 kernels) ----
    zero_init_kernel<<<1, 512, 0, stream>>>(bnacc, gcur);
    bucket_kernel<<<BG, 256, 0, stream>>>(e_src, e_dst, gcur, bP);
    sort_range_kernel<<<RNG2, 512, 0, stream>>>(bP, gcur, row_start, deg_inv, sorted);

    // ---- weights + fp16 x (merged) ----
    wx_kernel<<<WCB + GV, 256, 0, stream>>>(
        (const float*)d_in[15], (const float*)d_in[2], (const float*)d_in[3],   // res1_w(0), s1_wl(1), s1_wr(2)
        (const float*)d_in[17], (const float*)d_in[5], (const float*)d_in[6],   // res2_w(3), s2_wl(4), s2_wr(5)
        (const float*)d_in[8], (const float*)d_in[9],                            // s3_wl(6), s3_wr(7)
        (const float*)d_in[19], (const float*)d_in[21], (const float*)d_in[23], // ff1(8), ff2(9), clf(10)
        Wpl, x, Hw);

    // ---- block 1 ----
    aggregate_kernel<<<GA, 256, 0, stream>>>(Hw, row_start, sorted, deg_inv, Mh);
    fused_sage_kernel<<<GG, 256, 0, stream>>>(
        Mh, Hw, WH(1), WL(1), WH(2), WL(2), WH(0), WL(0), s1_b, res1_b, B0h, B1h, bnacc);
    bnrelures_kernel<<<GV8, 256, 0, stream>>>(B0h, B1h, bnacc, bn1_g, bn1_b, Hw);   // h1 -> Hw

    // ---- block 2 ----
    aggregate_kernel<<<GA, 256, 0, stream>>>(Hw, row_start, sorted, deg_inv, Mh);
    fused_sage_kernel<<<GG, 256, 0, stream>>>(
        Mh, Hw, WH(4), WL(4), WH(5), WL(5), WH(3), WL(3), s2_b, res2_b, B0h, B1h, bnacc + 256);
    bnrelures_kernel<<<GV8, 256, 0, stream>>>(B0h, B1h, bnacc + 256, bn2_g, bn2_b, Hw); // h2 -> Hw

    // ---- block 3 + head (fully fused) ----
    aggregate_kernel<<<GA, 256, 0, stream>>>(Hw, row_start, sorted, deg_inv, Mh);
    fused_block3_kernel<<<GG, 256, 0, stream>>>(
        Mh, Hw, WH(6), WL(6), WH(7), WL(7), WH(8), WL(8), WH(9), WL(9), WH(10), WL(10),
        s3_b, ff1_b, ff2_b, clf_b, out);
}

// Round 13
// 550.190 us; speedup vs baseline: 1.0542x; 1.0542x over previous
//
#include <hip/hip_runtime.h>
#include <hip/hip_fp16.h>

#define NN 100000
#define NE 1600000
#define KD 128
#define EPSF 1e-5f
#define RNG2 200                    // fine dst-ranges (1 sort block each)
#define RSZ2 500                    // nodes per range (200*500 = NN exactly)
#define BE 4096                     // edges per bucket block
#define BG ((NE + BE - 1) / BE)     // 391 bucket blocks
#define BCAP2 10000                 // per-range capacity (mean 8000, +22 sigma)
#define WPLANE 16384                // 128*128 weight plane (ushort elems)
#define LDK 136                     // LDS K-stride (128 + 8 pad)
#define WCB 168                     // wconv blocks (43008/256)

typedef __attribute__((ext_vector_type(8))) _Float16 f16x8;
typedef __attribute__((ext_vector_type(8))) unsigned short ushort8;
typedef __attribute__((ext_vector_type(4))) unsigned short ushort4v;
typedef __attribute__((ext_vector_type(4))) float f32x4;

// ---- fp16 helpers ----
__device__ __forceinline__ unsigned short f2h(float f) {
    __half h = __float2half_rn(f);
    return *reinterpret_cast<unsigned short*>(&h);
}
__device__ __forceinline__ float h2f(unsigned short u) {
    __half h;
    *reinterpret_cast<unsigned short*>(&h) = u;
    return __half2float(h);
}
__device__ __forceinline__ float2 h2f2(unsigned u) {
    __half2 h = *reinterpret_cast<const __half2*>(&u);
    return __half22float2(h);
}

// ---------------------------------------------------------------- init ----
__global__ void zero_init_kernel(float* __restrict__ bnacc, int* __restrict__ gcur) {
    int i = threadIdx.x;
    if (i < 512) bnacc[i] = 0.0f;
    if (i < RNG2) gcur[i] = 0;
}

// ---------------------------------------------------------- bucketing ----
// One pass over the edge list: append packed (src<<9 | dst_local) records to
// 200 fine-range buckets. Block chunk reservation via LDS hist + 1 global
// atomic per (range,block) -> dense-ish sequential bucket writes.
__global__ __launch_bounds__(256) void bucket_kernel(
    const int* __restrict__ src, const int* __restrict__ dst,
    int* __restrict__ gcur, unsigned* __restrict__ bP) {
    __shared__ int lhist[RNG2];
    __shared__ int lbase[RNG2];
    __shared__ int lcur[RNG2];
    const int t = threadIdx.x;
    const int e0 = blockIdx.x * BE;
    const int e1 = min(e0 + BE, NE);
    if (t < RNG2) { lhist[t] = 0; lcur[t] = 0; }
    __syncthreads();
    int dv[16], sv[16], rr[16];
    int nv = 0;
#pragma unroll
    for (int i = 0; i < 16; i++) {
        int e = e0 + i * 256 + t;
        if (e < e1) {
            int d = __builtin_nontemporal_load(&dst[e]);
            int s = __builtin_nontemporal_load(&src[e]);
            dv[i] = d; sv[i] = s;
            rr[i] = (int)((unsigned)d / RSZ2);
            nv = i + 1;              // validity is an i-prefix for fixed t
            atomicAdd(&lhist[rr[i]], 1);
        }
    }
    __syncthreads();
    if (t < RNG2) lbase[t] = lhist[t] ? atomicAdd(&gcur[t], lhist[t]) : 0;
    __syncthreads();
#pragma unroll
    for (int i = 0; i < 16; i++) {
        if (i < nv) {
            int r = rr[i];
            int p = lbase[r] + atomicAdd(&lcur[r], 1);
            if (p < BCAP2)
                bP[(size_t)r * BCAP2 + p] =
                    ((unsigned)sv[i] << 9) | (unsigned)(dv[i] - r * RSZ2);
        }
    }
}

// ------------------------------------------------- per-range LDS sort ----
// One block per range: LDS hist over 500 nodes -> exclusive scan -> emits
// row_start/deg_inv, then places edges into its PRIVATE disjoint slice of
// sorted_src (all writers of a cache line = this block -> lines flush once).
__global__ __launch_bounds__(512) void sort_range_kernel(
    const unsigned* __restrict__ bP, const int* __restrict__ gcur,
    int* __restrict__ row_start, float* __restrict__ deg_inv,
    int* __restrict__ sorted_src) {
    __shared__ int s[512];
    __shared__ int cnt[RSZ2];
    __shared__ int cur[RSZ2];
    __shared__ int sbase;
    const int r = blockIdx.x;
    const int t = threadIdx.x;

    // global base = prefix over the 200 range totals
    int v = (t < RNG2) ? gcur[t] : 0;
    s[t] = v;
    __syncthreads();
    for (int off = 1; off < 512; off <<= 1) {
        int u = (t >= off) ? s[t - off] : 0;
        __syncthreads();
        s[t] += u;
        __syncthreads();
    }
    if (t == 0) sbase = (r == 0) ? 0 : s[r - 1];
    if (t < RSZ2) cnt[t] = 0;
    __syncthreads();

    const int n = gcur[r];
    const unsigned* b = &bP[(size_t)r * BCAP2];
    for (int i = t; i < n; i += 512) {
        unsigned u = __builtin_nontemporal_load(&b[i]);
        atomicAdd(&cnt[u & 511u], 1);
    }
    __syncthreads();

    // exclusive scan of cnt[0..RSZ2)
    int c = (t < RSZ2) ? cnt[t] : 0;
    s[t] = c;
    __syncthreads();
    for (int off = 1; off < 512; off <<= 1) {
        int u = (t >= off) ? s[t - off] : 0;
        __syncthreads();
        s[t] += u;
        __syncthreads();
    }
    const int base = sbase;
    if (t < RSZ2) {
        int excl = s[t] - c;
        cur[t] = excl;
        int g = r * RSZ2 + t;
        row_start[g] = base + excl;
        deg_inv[g] = 1.0f / (float)(c > 1 ? c : 1);
    }
    if (r == RNG2 - 1 && t == 0) row_start[NN] = NE;
    __syncthreads();

    for (int i = t; i < n; i += 512) {
        unsigned u = __builtin_nontemporal_load(&b[i]);
        int d = (int)(u & 511u);
        int p = atomicAdd(&cur[d], 1);
        sorted_src[base + p] = (int)(u >> 9);
    }
}

// ---------------------------------------------------------- converters ----
// Merged: blocks [0,WCB) convert 11 weight matrices -> fp16 hi/lo planes in
// MFMA-FRAGMENT ORDER (element (col=cg*16+mm, k=ks*32+q*8+i) stored at
// ((cg*4+ks)*64 + q*16+mm)*8 + i); blocks [WCB,..) convert x fp32->fp16.
__global__ void wx_kernel(const float* w0, const float* w1, const float* w2,
                          const float* w3, const float* w4, const float* w5,
                          const float* w6, const float* w7, const float* w8,
                          const float* w9, const float* w10,
                          unsigned short* __restrict__ P,
                          const float* __restrict__ X, unsigned short* __restrict__ Xh) {
    if (blockIdx.x < WCB) {
        int i = blockIdx.x * 256 + threadIdx.x;  // float4 index
        if (i >= 43008) return;                  // 10*4096 + 2048
        int seg = i >> 12;
        const float* srcs[11] = {w0, w1, w2, w3, w4, w5, w6, w7, w8, w9, w10};
        const float* s = srcs[seg];
        int off = i - (seg << 12);
        float4 v = ((const float4*)s)[off];
        ushort4v h, l;
        h.x = f2h(v.x); l.x = f2h(v.x - h2f(h.x));
        h.y = f2h(v.y); l.y = f2h(v.y - h2f(h.y));
        h.z = f2h(v.z); l.z = f2h(v.z - h2f(h.z));
        h.w = f2h(v.w); l.w = f2h(v.w - h2f(h.w));
        // fragment-order output index
        int col = off >> 5;          // 0..127 (0..63 for clf)
        int k4  = off & 31;          // float4 along k
        int cg = col >> 4, mm = col & 15;
        int k = k4 * 4;
        int ks = k >> 5, q = (k >> 3) & 3, ii = k & 7;   // ii in {0,4}
        int po = ((cg * 4 + ks) * 64 + q * 16 + mm) * 8 + ii;
        *(ushort4v*)&P[(size_t)seg * WPLANE + po] = h;
        *(ushort4v*)&P[(size_t)(11 + seg) * WPLANE + po] = l;
    } else {
        int idx = (blockIdx.x - WCB) * 256 + threadIdx.x;
        if (idx >= NN * KD / 4) return;
        float4 v = ((const float4*)X)[idx];
        ushort4v h;
        h.x = f2h(v.x); h.y = f2h(v.y); h.z = f2h(v.z); h.w = f2h(v.w);
        *(ushort4v*)&Xh[(size_t)idx * 4] = h;
    }
}

// ------------------------------------------------------------ aggregate ----
// mean over in-neighbors. 16 lanes x uint4 (16B) per row, 8-deep unroll ->
// ~8KB in flight per wave (Little's law). fp32 accum, fp16 out. Plain store
// (R8 lesson: NT stores defeat L2 write combining).
__global__ void aggregate_kernel(const unsigned short* __restrict__ Xh,
                                 const int* __restrict__ row_start,
                                 const int* __restrict__ sorted_src,
                                 const float* __restrict__ deg_inv,
                                 unsigned short* __restrict__ Mh) {
    int node = blockIdx.x * 16 + (threadIdx.x >> 4);
    int lane = threadIdx.x & 15;
    if (node >= NN) return;
    int e0 = row_start[node];
    int e1 = row_start[node + 1];
    float4 a0 = {0, 0, 0, 0}, a1 = {0, 0, 0, 0};
    float4 b0 = {0, 0, 0, 0}, b1 = {0, 0, 0, 0};

    auto ld = [&](int e) -> uint4 {
        int s = sorted_src[e];
        return *(const uint4*)&Xh[(size_t)s * KD + lane * 8];
    };
    auto addq = [](float4& x, float4& y, uint4 u) {
        float2 p0 = h2f2(u.x), p1 = h2f2(u.y), p2 = h2f2(u.z), p3 = h2f2(u.w);
        x.x += p0.x; x.y += p0.y; x.z += p1.x; x.w += p1.y;
        y.x += p2.x; y.y += p2.y; y.z += p3.x; y.w += p3.y;
    };

    int e = e0;
    for (; e + 8 <= e1; e += 8) {
        uint4 u0 = ld(e + 0), u1 = ld(e + 1), u2 = ld(e + 2), u3 = ld(e + 3);
        uint4 u4 = ld(e + 4), u5 = ld(e + 5), u6 = ld(e + 6), u7 = ld(e + 7);
        addq(a0, a1, u0); addq(b0, b1, u1); addq(a0, a1, u2); addq(b0, b1, u3);
        addq(a0, a1, u4); addq(b0, b1, u5); addq(a0, a1, u6); addq(b0, b1, u7);
    }
    for (; e + 2 <= e1; e += 2) {
        uint4 u0 = ld(e + 0), u1 = ld(e + 1);
        addq(a0, a1, u0); addq(b0, b1, u1);
    }
    if (e < e1) { uint4 u = ld(e); addq(a0, a1, u); }

    float di = deg_inv[node];
    ushort8 o;
    o[0] = f2h((a0.x + b0.x) * di);
    o[1] = f2h((a0.y + b0.y) * di);
    o[2] = f2h((a0.z + b0.z) * di);
    o[3] = f2h((a0.w + b0.w) * di);
    o[4] = f2h((a1.x + b1.x) * di);
    o[5] = f2h((a1.y + b1.y) * di);
    o[6] = f2h((a1.z + b1.z) * di);
    o[7] = f2h((a1.w + b1.w) * di);
    *(ushort8*)&Mh[(size_t)node * KD + lane * 8] = o;
}

// ---------------------------------------------------- fused GEMM helpers ----
// Fragment layout (verified R4-R8): A[m=lane&15][k=quad*8+j]; C/D col=lane&15,
// row=quad*4+reg. LDS plane: [row 0..63][k 0..127], stride LDK (fp16).
// Weights pre-permuted to fragment order: load = base(cg,ks) + lane*16B.
// LDS staging kept (R12 lesson: direct-global A = 4x per-wave VMEM issue;
// block-shared LDS tile is the request-count amplifier-remover).

template <int NT>
__device__ __forceinline__ void product_A16(
    const unsigned short* P,
    const unsigned short* __restrict__ Wh, const unsigned short* __restrict__ Wl,
    int colb, int quad, int mm, f32x4 (&acc)[4][NT]) {
    const int l8 = (quad * 16 + mm) * 8;
    const int cg0 = colb >> 4;
#pragma unroll
    for (int ks = 0; ks < 4; ks++) {
        f16x8 a[4];
#pragma unroll
        for (int mt = 0; mt < 4; mt++)
            a[mt] = *(const f16x8*)&P[(mt * 16 + mm) * LDK + ks * 32 + quad * 8];
#pragma unroll
        for (int nt = 0; nt < NT; nt++) {
            size_t wo = (size_t)(((cg0 + nt) * 4 + ks) << 9) + l8;
            f16x8 wh = *(const f16x8*)&Wh[wo];
            f16x8 wl = *(const f16x8*)&Wl[wo];
#pragma unroll
            for (int mt = 0; mt < 4; mt++) {
                acc[mt][nt] = __builtin_amdgcn_mfma_f32_16x16x32_f16(a[mt], wh, acc[mt][nt], 0, 0, 0);
                acc[mt][nt] = __builtin_amdgcn_mfma_f32_16x16x32_f16(a[mt], wl, acc[mt][nt], 0, 0, 0);
            }
        }
    }
}

// dual product: two weight matrices share the A-fragment LDS reads
template <int NT>
__device__ __forceinline__ void product2_A16(
    const unsigned short* P,
    const unsigned short* __restrict__ W1h, const unsigned short* __restrict__ W1l,
    const unsigned short* __restrict__ W2h, const unsigned short* __restrict__ W2l,
    int colb, int quad, int mm, f32x4 (&acc1)[4][NT], f32x4 (&acc2)[4][NT]) {
    const int l8 = (quad * 16 + mm) * 8;
    const int cg0 = colb >> 4;
#pragma unroll
    for (int ks = 0; ks < 4; ks++) {
        f16x8 a[4];
#pragma unroll
        for (int mt = 0; mt < 4; mt++)
            a[mt] = *(const f16x8*)&P[(mt * 16 + mm) * LDK + ks * 32 + quad * 8];
#pragma unroll
        for (int nt = 0; nt < NT; nt++) {
            size_t wo = (size_t)(((cg0 + nt) * 4 + ks) << 9) + l8;
            f16x8 w1h = *(const f16x8*)&W1h[wo];
            f16x8 w1l = *(const f16x8*)&W1l[wo];
            f16x8 w2h = *(const f16x8*)&W2h[wo];
            f16x8 w2l = *(const f16x8*)&W2l[wo];
#pragma unroll
            for (int mt = 0; mt < 4; mt++) {
                acc1[mt][nt] = __builtin_amdgcn_mfma_f32_16x16x32_f16(a[mt], w1h, acc1[mt][nt], 0, 0, 0);
                acc1[mt][nt] = __builtin_amdgcn_mfma_f32_16x16x32_f16(a[mt], w1l, acc1[mt][nt], 0, 0, 0);
                acc2[mt][nt] = __builtin_amdgcn_mfma_f32_16x16x32_f16(a[mt], w2h, acc2[mt][nt], 0, 0, 0);
                acc2[mt][nt] = __builtin_amdgcn_mfma_f32_16x16x32_f16(a[mt], w2l, acc2[mt][nt], 0, 0, 0);
            }
        }
    }
}

// split-A product (A = Ah + Al fp16 planes, exact intermediates): 3 MFMA
template <int NT>
__device__ __forceinline__ void productS_A16(
    const unsigned short* Ph, const unsigned short* Pl,
    const unsigned short* __restrict__ Wh, const unsigned short* __restrict__ Wl,
    int colb, int quad, int mm, f32x4 (&acc)[4][NT]) {
    const int l8 = (quad * 16 + mm) * 8;
    const int cg0 = colb >> 4;
#pragma unroll
    for (int ks = 0; ks < 4; ks++) {
        f16x8 ah[4], al[4];
#pragma unroll
        for (int mt = 0; mt < 4; mt++) {
            int off = (mt * 16 + mm) * LDK + ks * 32 + quad * 8;
            ah[mt] = *(const f16x8*)&Ph[off];
            al[mt] = *(const f16x8*)&Pl[off];
        }
#pragma unroll
        for (int nt = 0; nt < NT; nt++) {
            size_t wo = (size_t)(((cg0 + nt) * 4 + ks) << 9) + l8;
            f16x8 wh = *(const f16x8*)&Wh[wo];
            f16x8 wl = *(const f16x8*)&Wl[wo];
#pragma unroll
            for (int mt = 0; mt < 4; mt++) {
                acc[mt][nt] = __builtin_amdgcn_mfma_f32_16x16x32_f16(ah[mt], wh, acc[mt][nt], 0, 0, 0);
                acc[mt][nt] = __builtin_amdgcn_mfma_f32_16x16x32_f16(ah[mt], wl, acc[mt][nt], 0, 0, 0);
                acc[mt][nt] = __builtin_amdgcn_mfma_f32_16x16x32_f16(al[mt], wh, acc[mt][nt], 0, 0, 0);
            }
        }
    }
}

// stage 64x128 fp16 tile -> LDS (pure 16B copy, no conversion)
__device__ __forceinline__ void stage_copy(const unsigned short* __restrict__ A, int i0, int t,
                                           unsigned short* P) {
#pragma unroll
    for (int p = 0; p < 4; p++) {
        int c = t + p * 256;
        int row = c >> 4, cc = (c & 15) * 8;
        int gi = min(i0 + row, NN - 1);
        *(ushort8*)&P[row * LDK + cc] = *(const ushort8*)&A[(size_t)gi * KD + cc];
    }
}

// T14 split: issue-early (global->reg), write-late (reg->LDS)
__device__ __forceinline__ void prefetch_h16(const unsigned short* __restrict__ A, int i0, int t,
                                             ushort8 (&pre)[4]) {
#pragma unroll
    for (int p = 0; p < 4; p++) {
        int c = t + p * 256;
        int row = c >> 4, cc = (c & 15) * 8;
        int gi = min(i0 + row, NN - 1);
        pre[p] = *(const ushort8*)&A[(size_t)gi * KD + cc];
    }
}
__device__ __forceinline__ void write_h16(const ushort8 (&pre)[4], int t, unsigned short* P) {
#pragma unroll
    for (int p = 0; p < 4; p++) {
        int c = t + p * 256;
        int row = c >> 4, cc = (c & 15) * 8;
        *(ushort8*)&P[row * LDK + cc] = pre[p];
    }
}

// ------------------------------------------------- fused sage+res+stats ----
// Dual LDS planes: 4 barriers. launch_bounds(256,4): R9-R12 A/B-verified
// optimum (VGPR 64, occ 29%, 64 us).
__global__ __launch_bounds__(256, 4) void fused_sage_kernel(
    const unsigned short* __restrict__ A1h, const unsigned short* __restrict__ A2h,
    const unsigned short* __restrict__ Wlh, const unsigned short* __restrict__ Wll,
    const unsigned short* __restrict__ Wrh, const unsigned short* __restrict__ Wrl,
    const unsigned short* __restrict__ Weh, const unsigned short* __restrict__ Wel,
    const float* __restrict__ bs, const float* __restrict__ br,
    unsigned short* __restrict__ B0h, unsigned short* __restrict__ B1h,
    float* __restrict__ bnacc) {
    __shared__ __align__(16) unsigned short P1[64 * LDK];
    __shared__ __align__(16) unsigned short P2[64 * LDK];
    const int t = threadIdx.x;
    const int i0 = blockIdx.x * 64;
    const int w = t >> 6, lane = t & 63, quad = lane >> 4, mm = lane & 15;
    const int colb = w * 32;

    // phase 1: mean @ Wl on P1; tile2 loads issued early, written to P2
    // AFTER product1 (vmcnt wait hides under MFMA), drains into barrier.
    stage_copy(A1h, i0, t, P1);
    ushort8 pre[4];
    prefetch_h16(A2h, i0, t, pre);
    __syncthreads();                       // P1 ready
    f32x4 accs[4][2] = {};
    product_A16<2>(P1, Wlh, Wll, colb, quad, mm, accs);
    write_h16(pre, t, P2);
    __syncthreads();                       // P2 ready
    f32x4 accr[4][2] = {};
    product2_A16<2>(P2, Wrh, Wrl, Weh, Wel, colb, quad, mm, accs, accr);

    // BN stats from fp32 accs (+bias); full-tile fast path (only last block partial)
    float s[2] = {0, 0}, q[2] = {0, 0};
    if (i0 + 64 <= NN) {
#pragma unroll
        for (int nt = 0; nt < 2; nt++) {
            float bvs = bs[colb + nt * 16 + mm];
#pragma unroll
            for (int mt = 0; mt < 4; mt++)
#pragma unroll
                for (int r = 0; r < 4; r++) {
                    float vs = accs[mt][nt][r] + bvs;
                    s[nt] += vs;
                    q[nt] += vs * vs;
                }
        }
    } else {
#pragma unroll
        for (int nt = 0; nt < 2; nt++) {
            float bvs = bs[colb + nt * 16 + mm];
#pragma unroll
            for (int mt = 0; mt < 4; mt++)
#pragma unroll
                for (int r = 0; r < 4; r++) {
                    if (i0 + mt * 16 + quad * 4 + r < NN) {
                        float vs = accs[mt][nt][r] + bvs;
                        s[nt] += vs;
                        q[nt] += vs * vs;
                    }
                }
        }
    }

    // epilogue: both results to LDS concurrently, one sync, dual row-stores
    __syncthreads();                       // all product reads of P1/P2 done
#pragma unroll
    for (int nt = 0; nt < 2; nt++) {
        int col = colb + nt * 16 + mm;
        float bvs = bs[col], bvr = br[col];
#pragma unroll
        for (int mt = 0; mt < 4; mt++)
#pragma unroll
            for (int r = 0; r < 4; r++) {
                int row = mt * 16 + quad * 4 + r;
                P1[row * LDK + col] = f2h(accs[mt][nt][r] + bvs);
                P2[row * LDK + col] = f2h(accr[mt][nt][r] + bvr);
            }
    }
    __syncthreads();
    {
        const int orow = t >> 2, ocs = (t & 3) * 32;
        const int go = i0 + orow;
        if (go < NN) {
#pragma unroll
            for (int j = 0; j < 4; j++) {
                *(ushort8*)&B0h[(size_t)go * KD + ocs + j * 8] =
                    *(const ushort8*)&P1[orow * LDK + ocs + j * 8];
                *(ushort8*)&B1h[(size_t)go * KD + ocs + j * 8] =
                    *(const ushort8*)&P2[orow * LDK + ocs + j * 8];
            }
        }
    }

#pragma unroll
    for (int nt = 0; nt < 2; nt++) {
        float ss = s[nt], qq = q[nt];
        ss += __shfl_xor(ss, 16); ss += __shfl_xor(ss, 32);
        qq += __shfl_xor(qq, 16); qq += __shfl_xor(qq, 32);
        if (quad == 0) {
            int col = colb + nt * 16 + mm;
            atomicAdd(&bnacc[col], ss);
            atomicAdd(&bnacc[128 + col], qq);
        }
    }
}

// ----------------------------------------- fused block3: sage3+ff1+ff2+clf ----
__global__ __launch_bounds__(256, 4) void fused_block3_kernel(
    const unsigned short* __restrict__ Mh, const unsigned short* __restrict__ Hw,
    const unsigned short* __restrict__ Wlh, const unsigned short* __restrict__ Wll,
    const unsigned short* __restrict__ Wrh, const unsigned short* __restrict__ Wrl,
    const unsigned short* __restrict__ F1h, const unsigned short* __restrict__ F1l,
    const unsigned short* __restrict__ F2h, const unsigned short* __restrict__ F2l,
    const unsigned short* __restrict__ Ch,  const unsigned short* __restrict__ Cl,
    const float* __restrict__ s3_b, const float* __restrict__ ff1_b,
    const float* __restrict__ ff2_b, const float* __restrict__ clf_b,
    float* __restrict__ out) {
    __shared__ __align__(16) unsigned short Ph[64 * LDK];
    __shared__ __align__(16) unsigned short Pl[64 * LDK];
    const int t = threadIdx.x;
    const int i0 = blockIdx.x * 64;
    const int w = t >> 6, lane = t & 63, quad = lane >> 4, mm = lane & 15;
    const int colb = w * 32;

    // write acc (+bias, opt relu) as exact fp16 hi/lo planes back into LDS
    auto write_lds = [&](f32x4 (&acc)[4][2], const float* bias, bool relu) {
#pragma unroll
        for (int nt = 0; nt < 2; nt++) {
            int col = colb + nt * 16 + mm;
            float bv = bias[col];
#pragma unroll
            for (int mt = 0; mt < 4; mt++)
#pragma unroll
                for (int r = 0; r < 4; r++) {
                    int row = mt * 16 + quad * 4 + r;
                    float v = acc[mt][nt][r] + bv;
                    if (relu) v = fmaxf(v, 0.0f);
                    unsigned short h = f2h(v);
                    Ph[row * LDK + col] = h;
                    Pl[row * LDK + col] = f2h(v - h2f(h));
                }
        }
    };

    // ---- sage3: mean @ Wl (Ph) + h @ Wr (Pl) + b; Hw written to Pl
    // after product1 so its vmcnt wait hides under MFMA.
    stage_copy(Mh, i0, t, Ph);
    ushort8 pre[4];
    prefetch_h16(Hw, i0, t, pre);
    __syncthreads();                       // Ph ready
    f32x4 acc[4][2] = {};
    product_A16<2>(Ph, Wlh, Wll, colb, quad, mm, acc);
    write_h16(pre, t, Pl);
    __syncthreads();                       // Pl ready
    product_A16<2>(Pl, Wrh, Wrl, colb, quad, mm, acc);
    __syncthreads();                       // all reads done before overwrite
    write_lds(acc, s3_b, false);
    __syncthreads();

    // ---- ff1 (+relu) ----
    f32x4 acc2[4][2] = {};
    productS_A16<2>(Ph, Pl, F1h, F1l, colb, quad, mm, acc2);
    __syncthreads();
    write_lds(acc2, ff1_b, true);
    __syncthreads();

    // ---- ff2 ----
    f32x4 acc3[4][2] = {};
    productS_A16<2>(Ph, Pl, F2h, F2l, colb, quad, mm, acc3);
    __syncthreads();
    write_lds(acc3, ff2_b, false);
    __syncthreads();

    // ---- clf (NOUT=64): waves cover cols w*16..w*16+15 ----
    f32x4 acc4[4][1] = {};
    productS_A16<1>(Ph, Pl, Ch, Cl, w * 16, quad, mm, acc4);
    __syncthreads();                       // LDS reads done; reuse Ph as f32 region
    {
        float* Pf = (float*)Ph;            // [64][68] f32 (68-stride kills bank clash)
        int col = w * 16 + mm;
        float bv = clf_b[col];
#pragma unroll
        for (int mt = 0; mt < 4; mt++)
#pragma unroll
            for (int r = 0; r < 4; r++)
                Pf[(mt * 16 + quad * 4 + r) * 68 + col] = acc4[mt][0][r] + bv;
        __syncthreads();
        int orow = t >> 2, of4 = (t & 3) * 4;
        if (i0 + orow < NN) {
#pragma unroll
            for (int j = 0; j < 4; j++)
                *(float4*)&out[(size_t)(i0 + orow) * 64 + (of4 + j) * 4] =
                    *(const float4*)&Pf[orow * 68 + (of4 + j) * 4];
        }
    }
}

// ------------------------------------------------------------------ BN ----
// h = relu(Y*scale+shift)+R -> fp16, 8 elems/thread; BN finalize inline from
// bnacc (1KB, L2-hot) -- replaces the separate bnfinal dispatch.
__global__ void bnrelures_kernel(const unsigned short* __restrict__ Y,
                                 const unsigned short* __restrict__ R,
                                 const float* __restrict__ acc,
                                 const float* __restrict__ g,
                                 const float* __restrict__ b,
                                 unsigned short* __restrict__ Hw) {
    int idx = blockIdx.x * blockDim.x + threadIdx.x;
    const int total = NN * KD / 8;
    if (idx >= total) return;
    int cg = idx & 15;                       // 16 col-groups of 8
    float sc[8], sh[8];
#pragma unroll
    for (int j = 0; j < 8; j++) {
        int col = cg * 8 + j;
        float mean = acc[col] * (1.0f / NN);
        float var = acc[128 + col] * (1.0f / NN) - mean * mean;
        float s = g[col] * rsqrtf(var + EPSF);
        sc[j] = s;
        sh[j] = b[col] - mean * s;
    }
    ushort8 y = *(const ushort8*)&Y[(size_t)idx * 8];
    ushort8 r = *(const ushort8*)&R[(size_t)idx * 8];
    ushort8 hh;
#pragma unroll
    for (int j = 0; j < 8; j++) {
        float f = fmaxf(h2f(y[j]) * sc[j] + sh[j], 0.0f) + h2f(r[j]);
        hh[j] = f2h(f);
    }
    *(ushort8*)&Hw[(size_t)idx * 8] = hh;
}

// --------------------------------------------------------------- launch ----
extern "C" void kernel_launch(void* const* d_in, const int* in_sizes, int n_in,
                              void* d_out, int out_size, void* d_ws, size_t ws_size,
                              hipStream_t stream) {
    const float* x      = (const float*)d_in[0];
    const int*   ei     = (const int*)d_in[1];
    const int*   e_src  = ei;
    const int*   e_dst  = ei + NE;
    const float* s1_b   = (const float*)d_in[4];
    const float* s2_b   = (const float*)d_in[7];
    const float* s3_b   = (const float*)d_in[10];
    const float* bn1_g  = (const float*)d_in[11];
    const float* bn1_b  = (const float*)d_in[12];
    const float* bn2_g  = (const float*)d_in[13];
    const float* bn2_b  = (const float*)d_in[14];
    const float* res1_b = (const float*)d_in[16];
    const float* res2_b = (const float*)d_in[18];
    const float* ff1_b  = (const float*)d_in[20];
    const float* ff2_b  = (const float*)d_in[22];
    const float* clf_b  = (const float*)d_in[24];
    float* out = (float*)d_out;

    // workspace carve-up (256B aligned)
    char* w = (char*)d_ws;
    auto alloc = [&](size_t bytes) { char* p = w; w += (bytes + 255) & ~(size_t)255; return p; };
    unsigned short* B0h = (unsigned short*)alloc((size_t)NN * KD * 2);  // sage out fp16
    unsigned short* B1h = (unsigned short*)alloc((size_t)NN * KD * 2);  // res out fp16
    unsigned short* Mh  = (unsigned short*)alloc((size_t)NN * KD * 2);  // mean fp16
    unsigned short* Hw  = (unsigned short*)alloc((size_t)NN * KD * 2);  // x/h fp16
    int*   row_start = (int*)alloc((NN + 1) * 4);
    int*   sorted    = (int*)alloc((size_t)NE * 4);
    unsigned* bP     = (unsigned*)alloc((size_t)RNG2 * BCAP2 * 4);  // edge buckets (8 MB)
    int*   gcur      = (int*)alloc(RNG2 * 4);
    float* deg_inv   = (float*)alloc(NN * 4);
    float* bnacc     = (float*)alloc(512 * 4);
    unsigned short* Wpl = (unsigned short*)alloc((size_t)22 * WPLANE * 2);

    auto WH = [&](int j) { return Wpl + (size_t)j * WPLANE; };
    auto WL = [&](int j) { return Wpl + (size_t)(11 + j) * WPLANE; };

    const int GG = (NN + 63) / 64;                 // 1563 fused-GEMM blocks
    const int GA = (NN + 15) / 16;                 // 6250 aggregate blocks
    const int GV = (NN * KD / 4 + 255) / 256;      // 12500 xhalf blocks
    const int GV8 = (NN * KD / 8 + 255) / 256;

    // ---- CSR build: bucket -> per-range LDS counting sort (2 kernels) ----
    zero_init_kernel<<<1, 512, 0, stream>>>(bnacc, gcur);
    bucket_kernel<<<BG, 256, 0, stream>>>(e_src, e_dst, gcur, bP);
    sort_range_kernel<<<RNG2, 512, 0, stream>>>(bP, gcur, row_start, deg_inv, sorted);

    // ---- weights + fp16 x (merged) ----
    wx_kernel<<<WCB + GV, 256, 0, stream>>>(
        (const float*)d_in[15], (const float*)d_in[2], (const float*)d_in[3],   // res1_w(0), s1_wl(1), s1_wr(2)
        (const float*)d_in[17], (const float*)d_in[5], (const float*)d_in[6],   // res2_w(3), s2_wl(4), s2_wr(5)
        (const float*)d_in[8], (const float*)d_in[9],                            // s3_wl(6), s3_wr(7)
        (const float*)d_in[19], (const float*)d_in[21], (const float*)d_in[23], // ff1(8), ff2(9), clf(10)
        Wpl, x, Hw);

    // ---- block 1 ----
    aggregate_kernel<<<GA, 256, 0, stream>>>(Hw, row_start, sorted, deg_inv, Mh);
    fused_sage_kernel<<<GG, 256, 0, stream>>>(
        Mh, Hw, WH(1), WL(1), WH(2), WL(2), WH(0), WL(0), s1_b, res1_b, B0h, B1h, bnacc);
    bnrelures_kernel<<<GV8, 256, 0, stream>>>(B0h, B1h, bnacc, bn1_g, bn1_b, Hw);   // h1 -> Hw

    // ---- block 2 ----
    aggregate_kernel<<<GA, 256, 0, stream>>>(Hw, row_start, sorted, deg_inv, Mh);
    fused_sage_kernel<<<GG, 256, 0, stream>>>(
        Mh, Hw, WH(4), WL(4), WH(5), WL(5), WH(3), WL(3), s2_b, res2_b, B0h, B1h, bnacc + 256);
    bnrelures_kernel<<<GV8, 256, 0, stream>>>(B0h, B1h, bnacc + 256, bn2_g, bn2_b, Hw); // h2 -> Hw

    // ---- block 3 + head (fully fused) ----
    aggregate_kernel<<<GA, 256, 0, stream>>>(Hw, row_start, sorted, deg_inv, Mh);
    fused_block3_kernel<<<GG, 256, 0, stream>>>(
        Mh, Hw, WH(6), WL(6), WH(7), WL(7), WH(8), WL(8), WH(9), WL(9), WH(10), WL(10),
        s3_b, ff1_b, ff2_b, clf_b, out);
}